// Round 11
// baseline (115.693 us; speedup 1.0000x reference)
//
#include <hip/hip_runtime.h>
#include <hip/hip_bf16.h>

// ContrastiveLoss: B=4096 rows, D=128 feature dim, C=100 classes.
// loss = -(1/B^2) * sum_k S_k * w_{l_k},  w_c = count_c/(count_c+1e-12)
//   S_k  = sum_j logits[k,j] - B*m_k - B*log(Z_k + 1e-12)
//   logits[k,j] = w_k . a_j,  w_k = (a_k + (a_k @ Cov[l_k]) / (2 T^2)) / T
// 3 dispatches: prep (bf16 conv of A + W build + ticket zero; R8-proven,
// at the L3-BW roofline for the 268 MB Cov gather), main (MFMA flash
// logits, XOR-swizzled LDS + A prefetch, R8-proven; partials [chunk][row]),
// tail (thread-per-row merge -> S_k, 16-block ticket -> in-kernel loss).
// LESSONS: (R4) heavy fp64 tails fused into the MFMA kernel wreck regalloc
// (VGPR 68, spills). (R7) single-address tickets at 4096-block scale
// serialize (~145us) — 16-block tickets are fine. (R6/R9) class-sorted Cov
// grouping and (R10) bf16-Cov+conv-node are both net-neutral-to-negative:
// fp32 prep is already at the L3 ceiling and every extra node costs ~5us.

#define DIM 128
#define TEMP 0.07f

typedef __attribute__((ext_vector_type(8))) short short8;
typedef __attribute__((ext_vector_type(4))) float floatx4;

static __device__ __forceinline__ unsigned short f2bf(float f) {
    __hip_bfloat16 h = __float2bfloat16(f);
    union { __hip_bfloat16 h; unsigned short u; } c;
    c.h = h;
    return c.u;
}

// 2 rows per block (256 threads). Writes Abf (bf16 copy of A) and
// Wbf = bf16((a + (a @ Cov[l]) / (2T^2)) / T). Block 0 zeroes the ticket.
// (R8-proven structure: 2048 blocks = 32 waves/CU on the Cov gather.)
__global__ __launch_bounds__(256) void prep_kernel(
    const float* __restrict__ A, const int* __restrict__ labels,
    const float* __restrict__ Cov, unsigned short* __restrict__ Wbf,
    unsigned short* __restrict__ Abf, int* __restrict__ ticket) {
    const float inv2t2 = 1.0f / (2.0f * TEMP * TEMP);
    const float invt = 1.0f / TEMP;
    const int sub = threadIdx.x >> 7;   // which of 2 rows
    const int e = threadIdx.x & 127;
    const int i = blockIdx.x * 2 + sub;
    if (blockIdx.x == 0 && threadIdx.x == 0) *ticket = 0;
    __shared__ float a[2][DIM];
    float av = A[(size_t)i * DIM + e];
    a[sub][e] = av;
    Abf[(size_t)i * DIM + e] = f2bf(av);
    __syncthreads();
    int c = labels[i];
    const float* Cp = Cov + (size_t)c * (DIM * DIM) + e;
    float acc = 0.0f;
#pragma unroll 8
    for (int d = 0; d < DIM; ++d) {
        acc = fmaf(a[sub][d], Cp[(size_t)d * DIM], acc);
    }
    Wbf[(size_t)i * DIM + e] = f2bf((av + acc * inv2t2) * invt);
}

// Block = 4 waves (2M x 2N). Block tile: 128 k-rows x 64 j-cols, K=128
// unrolled. Wave tile: 64x32 via 4(m) x 2(n) mfma_f32_16x16x32_bf16.
// LDS: PITCH=128, 16B-chunk XOR swizzle -> conflict-free ds_read_b128.
// A-tile register prefetch hides the vmcnt drain in compute. (R8-proven;
// only the partial-store layout is [chunk][row] for the coalesced tail.)
__global__ __launch_bounds__(256, 2) void main_kernel(
    const unsigned short* __restrict__ Wbf, const unsigned short* __restrict__ Abf,
    float* __restrict__ mP, float* __restrict__ zP, float* __restrict__ sP,
    int Jsplit, int JSWEEP, int nP, int B) {
    __shared__ __align__(16) unsigned short sW[128 * 128];  // 32 KB
    __shared__ __align__(16) unsigned short sA[64 * 128];   // 16 KB

    const int mb = blockIdx.x / Jsplit;
    const int jsp = blockIdx.x % Jsplit;
    const int rowBase = mb * 128;
    const int t = threadIdx.x;
    const int wave = t >> 6, lane = t & 63, quad = lane >> 4, l16 = lane & 15;
    const int waveM = wave >> 1, waveN = wave & 1;

    // stage W tile (128 rows x 128 bf16), swizzled, once
    {
        int row = t >> 1, half = t & 1, rsw = row & 15;
        const unsigned short* src = Wbf + (size_t)(rowBase + row) * DIM + half * 64;
        unsigned short* dstrow = sW + row * 128;
#pragma unroll
        for (int i = 0; i < 8; i++) {
            int c = half * 8 + i;
            *(short8*)(dstrow + ((c ^ rsw) << 3)) = *(const short8*)(src + i * 8);
        }
    }

    float run_m[4][4], run_Z[4][4], run_s[4][4];
#pragma unroll
    for (int a = 0; a < 4; a++)
#pragma unroll
        for (int r = 0; r < 4; r++) {
            run_m[a][r] = -3.4e38f; run_Z[a][r] = 0.f; run_s[a][r] = 0.f;
        }

    // A-tile staging descriptors (thread -> row, quarter)
    const int arow = t >> 2, aq = t & 3, arsw = arow & 15;
    const unsigned short* asrc0 =
        Abf + (size_t)(jsp * JSWEEP * 64 + arow) * DIM + aq * 32;
    unsigned short* adst = sA + arow * 128;

    short8 pre[4];
#pragma unroll
    for (int i = 0; i < 4; i++) pre[i] = *(const short8*)(asrc0 + i * 8);

    const unsigned short* myW = sW + (size_t)(waveM * 64 + l16) * 128;
    const unsigned short* myA = sA + (size_t)(waveN * 32 + l16) * 128;

    for (int js = 0; js < JSWEEP; ++js) {
        __syncthreads();  // sA free to overwrite (prefetched loads long done)
#pragma unroll
        for (int i = 0; i < 4; i++) {
            int c = aq * 4 + i;
            *(short8*)(adst + ((c ^ arsw) << 3)) = pre[i];
        }
        __syncthreads();  // sA (and sW on first iter) ready

        if (js + 1 < JSWEEP) {  // issue next tile's loads; drain hides in compute
            const unsigned short* nsrc = asrc0 + (size_t)(js + 1) * 64 * DIM;
#pragma unroll
            for (int i = 0; i < 4; i++) pre[i] = *(const short8*)(nsrc + i * 8);
        }

        floatx4 acc[4][2];
#pragma unroll
        for (int mt = 0; mt < 4; mt++)
#pragma unroll
            for (int nt = 0; nt < 2; nt++) acc[mt][nt] = (floatx4)0.f;

#pragma unroll
        for (int kst = 0; kst < 4; ++kst) {
            const int coff = (((kst << 2) | quad) ^ l16) << 3;
            short8 bfrag[2];
#pragma unroll
            for (int nt = 0; nt < 2; nt++)
                bfrag[nt] = *(const short8*)(myA + nt * 16 * 128 + coff);
#pragma unroll
            for (int mt = 0; mt < 4; mt++) {
                short8 afrag = *(const short8*)(myW + mt * 16 * 128 + coff);
#pragma unroll
                for (int nt = 0; nt < 2; nt++)
                    acc[mt][nt] = __builtin_amdgcn_mfma_f32_16x16x32_bf16(
                        afrag, bfrag[nt], acc[mt][nt], 0, 0, 0);
            }
        }

        // per-lane online softmax update (lane's 2 columns only; no shfl)
#pragma unroll
        for (int mt = 0; mt < 4; mt++)
#pragma unroll
            for (int r = 0; r < 4; r++) {
                float v0 = acc[mt][0][r], v1 = acc[mt][1][r];
                float tm = fmaxf(v0, v1);
                float nm = fmaxf(run_m[mt][r], tm);
                run_Z[mt][r] = run_Z[mt][r] * __expf(run_m[mt][r] - nm)
                             + __expf(v0 - nm) + __expf(v1 - nm);
                run_m[mt][r] = nm;
                run_s[mt][r] += v0 + v1;
            }
    }

    // merge across the 16 lanes sharing each row, write partials [chunk][row]
    const int chunk = jsp * 2 + waveN;
#pragma unroll
    for (int mt = 0; mt < 4; mt++)
#pragma unroll
        for (int r = 0; r < 4; r++) {
            float m = run_m[mt][r], Z = run_Z[mt][r], s = run_s[mt][r];
#pragma unroll
            for (int mask = 1; mask < 16; mask <<= 1) {
                float om = __shfl_xor(m, mask);
                float oZ = __shfl_xor(Z, mask);
                float os = __shfl_xor(s, mask);
                float nm = fmaxf(m, om);
                Z = Z * __expf(m - nm) + oZ * __expf(om - nm);
                m = nm;
                s += os;
            }
            if (l16 == r) {
                int row = rowBase + waveM * 64 + mt * 16 + quad * 4 + r;
                size_t idx = (size_t)chunk * B + row;
                mP[idx] = m; zP[idx] = Z; sP[idx] = s;
            }
        }
}

// 16 blocks x 256 threads: thread owns row k, merges nP partials (coalesced
// [chunk][row] reads), writes S_k. Last block (16-increment ticket) builds
// the label histogram and computes the final loss. (R10-proven.)
__global__ __launch_bounds__(256) void tail_kernel(
    const float* __restrict__ mP, const float* __restrict__ zP,
    const float* __restrict__ sP, const int* __restrict__ labels,
    double* __restrict__ Sk, int* __restrict__ ticket,
    float* __restrict__ out, int B, int nP) {
    __shared__ int flag;
    __shared__ int hist[128];
    __shared__ double sh[256];
    const int t = threadIdx.x;
    const int k = blockIdx.x * 256 + t;

    float m = mP[k], Z = zP[k], s = sP[k];
    for (int p = 1; p < nP; ++p) {
        size_t idx = (size_t)p * B + k;
        float mi = mP[idx];
        float nm = fmaxf(m, mi);
        Z = Z * __expf(m - nm) + zP[idx] * __expf(mi - nm);
        m = nm;
        s += sP[idx];
    }
    Sk[k] = (double)s - (double)B * (double)m
            - (double)B * log((double)Z + 1e-12);

    __threadfence();
    __syncthreads();
    if (t == 0) flag = (atomicAdd(ticket, 1) == (int)gridDim.x - 1);
    __syncthreads();
    if (!flag) return;
    __threadfence();  // acquire: other blocks' Sk stores

    if (t < 128) hist[t] = 0;
    __syncthreads();
    for (int i = t; i < B; i += 256) atomicAdd(&hist[labels[i]], 1);
    __syncthreads();
    double acc = 0.0;
    for (int i = t; i < B; i += 256) {
        double cnt = (double)hist[labels[i]];
        acc += Sk[i] * (cnt / (cnt + 1e-12));
    }
    sh[t] = acc;
    __syncthreads();
    for (int o = 128; o > 0; o >>= 1) {
        if (t < o) sh[t] += sh[t + o];
        __syncthreads();
    }
    if (t == 0) out[0] = (float)(-sh[0] / ((double)B * (double)B));
}

extern "C" void kernel_launch(void* const* d_in, const int* in_sizes, int n_in,
                              void* d_out, int out_size, void* d_ws, size_t ws_size,
                              hipStream_t stream) {
    const float* A = (const float*)d_in[0];
    const int* labels = (const int*)d_in[1];
    const float* Cov = (const float*)d_in[2];
    float* out = (float*)d_out;

    int B = in_sizes[0] / DIM;            // 4096
    int Jsplit = 16;
    int JSWEEP = B / (Jsplit * 64);       // 4
    int nP = Jsplit * 2;                  // 32 partials per row

    char* ws = (char*)d_ws;
    unsigned short* Wbf = (unsigned short*)ws;                       // B*128 bf16
    unsigned short* Abf = Wbf + (size_t)B * DIM;                     // B*128 bf16
    float* mP = (float*)(Abf + (size_t)B * DIM);                     // nP*B f32
    float* zP = mP + (size_t)B * nP;
    float* sP = zP + (size_t)B * nP;
    double* Sk = (double*)(sP + (size_t)B * nP);                     // B doubles
    int* ticket = (int*)(Sk + B);                                    // 1 int

    prep_kernel<<<B / 2, 256, 0, stream>>>(A, labels, Cov, Wbf, Abf, ticket);
    main_kernel<<<(B / 128) * Jsplit, 256, 0, stream>>>(Wbf, Abf, mP, zP, sP,
                                                        Jsplit, JSWEEP, nP, B);
    tail_kernel<<<B / 256, 256, 0, stream>>>(mP, zP, sP, labels, Sk, ticket,
                                             out, B, nP);
}

// Round 13
// 101.599 us; speedup vs baseline: 1.1387x; 1.1387x over previous
//
#include <hip/hip_runtime.h>
#include <hip/hip_bf16.h>

// ContrastiveLoss: B=4096 rows, D=128 feature dim, C=100 classes.
// loss = -(1/B^2) * sum_k S_k * w_{l_k},  w_c = count_c/(count_c+1e-12)
//   S_k  = sum_j logits[k,j] - B*m_k - B*log(Z_k + 1e-12)
//   logits[k,j] = w_k . a_j,  w_k = (a_k + (a_k @ Cov[l_k]) / (2 T^2)) / T
// R8 structure (measured optimum across 13 variants): 4 dispatches —
// prep (bf16 conv of A + W build; L3-BW-bound on the 268 MB Cov gather),
// main (MFMA flash logits, XOR-swizzled LDS + A-tile register prefetch),
// combine (per-row merge -> S_k, no atomics), final (1-block weighted sum).
// LESSONS: (R4) fp64 tails fused into the MFMA kernel wreck regalloc
// (VGPR 68, spills, 115us). (R7) single-address tickets at 4096-block scale
// serialize (~145us). (R6/R9) class-sorted Cov grouping neutral (Cov is
// cache-resident). (R10) bf16-Cov + extra conv node net-negative. (R11)
// combine+final ticket fusion regressed (+15us). (R12) cooperative launch
// fails silently in this harness. R8's exact shape beat all of them.

#define DIM 128
#define TEMP 0.07f

typedef __attribute__((ext_vector_type(8))) short short8;
typedef __attribute__((ext_vector_type(4))) float floatx4;

static __device__ __forceinline__ unsigned short f2bf(float f) {
    __hip_bfloat16 h = __float2bfloat16(f);
    union { __hip_bfloat16 h; unsigned short u; } c;
    c.h = h;
    return c.u;
}

// 2 rows per block (256 threads). Writes Abf (bf16 copy of A) and
// Wbf = bf16((a + (a @ Cov[l]) / (2T^2)) / T).
__global__ __launch_bounds__(256) void prep_kernel(
    const float* __restrict__ A, const int* __restrict__ labels,
    const float* __restrict__ Cov, unsigned short* __restrict__ Wbf,
    unsigned short* __restrict__ Abf) {
    const float inv2t2 = 1.0f / (2.0f * TEMP * TEMP);
    const float invt = 1.0f / TEMP;
    const int sub = threadIdx.x >> 7;   // which of 2 rows
    const int e = threadIdx.x & 127;
    const int i = blockIdx.x * 2 + sub;
    __shared__ float a[2][DIM];
    float av = A[(size_t)i * DIM + e];
    a[sub][e] = av;
    Abf[(size_t)i * DIM + e] = f2bf(av);
    __syncthreads();
    int c = labels[i];
    const float* Cp = Cov + (size_t)c * (DIM * DIM) + e;
    float acc = 0.0f;
#pragma unroll 8
    for (int d = 0; d < DIM; ++d) {
        acc = fmaf(a[sub][d], Cp[(size_t)d * DIM], acc);
    }
    Wbf[(size_t)i * DIM + e] = f2bf((av + acc * inv2t2) * invt);
}

// Block = 4 waves (2M x 2N). Block tile: 128 k-rows x 64 j-cols, K=128
// unrolled. Wave tile: 64x32 via 4(m) x 2(n) mfma_f32_16x16x32_bf16.
// LDS: PITCH=128, 16B-chunk XOR swizzle (chunk c of row r at c^(r&15)) ->
// fragment ds_read_b128 conflict-free (16 lanes hit 16 distinct chunks).
// A-tile staged via register prefetch issued after the compute barrier so
// the vmcnt drain overlaps MFMA+softmax of the current tile.
// Per-lane online softmax; 16-lane merge at end. grid = 32 mb x 16 jsp.
__global__ __launch_bounds__(256, 2) void main_kernel(
    const unsigned short* __restrict__ Wbf, const unsigned short* __restrict__ Abf,
    float* __restrict__ mP, float* __restrict__ zP, float* __restrict__ sP,
    int Jsplit, int JSWEEP, int nP) {
    __shared__ __align__(16) unsigned short sW[128 * 128];  // 32 KB
    __shared__ __align__(16) unsigned short sA[64 * 128];   // 16 KB

    const int mb = blockIdx.x / Jsplit;
    const int jsp = blockIdx.x % Jsplit;
    const int rowBase = mb * 128;
    const int t = threadIdx.x;
    const int wave = t >> 6, lane = t & 63, quad = lane >> 4, l16 = lane & 15;
    const int waveM = wave >> 1, waveN = wave & 1;

    // stage W tile (128 rows x 128 bf16), swizzled, once
    {
        int row = t >> 1, half = t & 1, rsw = row & 15;
        const unsigned short* src = Wbf + (size_t)(rowBase + row) * DIM + half * 64;
        unsigned short* dstrow = sW + row * 128;
#pragma unroll
        for (int i = 0; i < 8; i++) {
            int c = half * 8 + i;
            *(short8*)(dstrow + ((c ^ rsw) << 3)) = *(const short8*)(src + i * 8);
        }
    }

    float run_m[4][4], run_Z[4][4], run_s[4][4];
#pragma unroll
    for (int a = 0; a < 4; a++)
#pragma unroll
        for (int r = 0; r < 4; r++) {
            run_m[a][r] = -3.4e38f; run_Z[a][r] = 0.f; run_s[a][r] = 0.f;
        }

    // A-tile staging descriptors (thread -> row, quarter)
    const int arow = t >> 2, aq = t & 3, arsw = arow & 15;
    const unsigned short* asrc0 =
        Abf + (size_t)(jsp * JSWEEP * 64 + arow) * DIM + aq * 32;
    unsigned short* adst = sA + arow * 128;

    short8 pre[4];
#pragma unroll
    for (int i = 0; i < 4; i++) pre[i] = *(const short8*)(asrc0 + i * 8);

    const unsigned short* myW = sW + (size_t)(waveM * 64 + l16) * 128;
    const unsigned short* myA = sA + (size_t)(waveN * 32 + l16) * 128;

    for (int js = 0; js < JSWEEP; ++js) {
        __syncthreads();  // sA free to overwrite (prefetched loads long done)
#pragma unroll
        for (int i = 0; i < 4; i++) {
            int c = aq * 4 + i;
            *(short8*)(adst + ((c ^ arsw) << 3)) = pre[i];
        }
        __syncthreads();  // sA (and sW on first iter) ready

        if (js + 1 < JSWEEP) {  // issue next tile's loads; drain hides in compute
            const unsigned short* nsrc = asrc0 + (size_t)(js + 1) * 64 * DIM;
#pragma unroll
            for (int i = 0; i < 4; i++) pre[i] = *(const short8*)(nsrc + i * 8);
        }

        floatx4 acc[4][2];
#pragma unroll
        for (int mt = 0; mt < 4; mt++)
#pragma unroll
            for (int nt = 0; nt < 2; nt++) acc[mt][nt] = (floatx4)0.f;

#pragma unroll
        for (int kst = 0; kst < 4; ++kst) {
            const int coff = (((kst << 2) | quad) ^ l16) << 3;
            short8 bfrag[2];
#pragma unroll
            for (int nt = 0; nt < 2; nt++)
                bfrag[nt] = *(const short8*)(myA + nt * 16 * 128 + coff);
#pragma unroll
            for (int mt = 0; mt < 4; mt++) {
                short8 afrag = *(const short8*)(myW + mt * 16 * 128 + coff);
#pragma unroll
                for (int nt = 0; nt < 2; nt++)
                    acc[mt][nt] = __builtin_amdgcn_mfma_f32_16x16x32_bf16(
                        afrag, bfrag[nt], acc[mt][nt], 0, 0, 0);
            }
        }

        // per-lane online softmax update (lane's 2 columns only; no shfl)
#pragma unroll
        for (int mt = 0; mt < 4; mt++)
#pragma unroll
            for (int r = 0; r < 4; r++) {
                float v0 = acc[mt][0][r], v1 = acc[mt][1][r];
                float tm = fmaxf(v0, v1);
                float nm = fmaxf(run_m[mt][r], tm);
                run_Z[mt][r] = run_Z[mt][r] * __expf(run_m[mt][r] - nm)
                             + __expf(v0 - nm) + __expf(v1 - nm);
                run_m[mt][r] = nm;
                run_s[mt][r] += v0 + v1;
            }
    }

    // merge across the 16 lanes sharing each row, then write partials
    const int chunk = jsp * 2 + waveN;
#pragma unroll
    for (int mt = 0; mt < 4; mt++)
#pragma unroll
        for (int r = 0; r < 4; r++) {
            float m = run_m[mt][r], Z = run_Z[mt][r], s = run_s[mt][r];
#pragma unroll
            for (int mask = 1; mask < 16; mask <<= 1) {
                float om = __shfl_xor(m, mask);
                float oZ = __shfl_xor(Z, mask);
                float os = __shfl_xor(s, mask);
                float nm = fmaxf(m, om);
                Z = Z * __expf(m - nm) + oZ * __expf(om - nm);
                m = nm;
                s += os;
            }
            if (l16 == r) {
                int row = rowBase + waveM * 64 + mt * 16 + quad * 4 + r;
                size_t idx = (size_t)row * nP + chunk;
                mP[idx] = m; zP[idx] = Z; sP[idx] = s;
            }
        }
}

// One wave per row k: merge nP partial (m,Z,s) triples, write S_k (double).
__global__ __launch_bounds__(64) void combine_kernel(
    const float* __restrict__ mP, const float* __restrict__ zP,
    const float* __restrict__ sP, double* __restrict__ Sk, int B, int nP) {
    int k = blockIdx.x;
    int l = threadIdx.x;
    float m = -3.4e38f, Z = 0.0f, s = 0.0f;
    if (l < nP) {
        size_t idx = (size_t)k * nP + l;
        m = mP[idx]; Z = zP[idx]; s = sP[idx];
    }
    float M = m;
#pragma unroll
    for (int o = 32; o > 0; o >>= 1) M = fmaxf(M, __shfl_xor(M, o));
    float zt = Z * __expf(m - M);
    float st = s;
#pragma unroll
    for (int o = 32; o > 0; o >>= 1) {
        zt += __shfl_xor(zt, o);
        st += __shfl_xor(st, o);
    }
    if (l == 0) {
        Sk[k] = (double)st - (double)B * (double)M
                - (double)B * log((double)zt + 1e-12);
    }
}

// One block: histogram labels in LDS, then loss = -(1/B^2) sum_k S_k * w_{l_k}.
__global__ __launch_bounds__(1024) void final_kernel(
    const double* __restrict__ Sk, const int* __restrict__ labels,
    float* __restrict__ out, int B) {
    __shared__ int hist[128];
    __shared__ double sh[1024];
    int t = threadIdx.x;
    if (t < 128) hist[t] = 0;
    __syncthreads();
    for (int i = t; i < B; i += 1024) atomicAdd(&hist[labels[i]], 1);
    __syncthreads();
    double acc = 0.0;
    for (int i = t; i < B; i += 1024) {
        double cnt = (double)hist[labels[i]];
        acc += Sk[i] * (cnt / (cnt + 1e-12));
    }
    sh[t] = acc;
    __syncthreads();
    for (int o = 512; o > 0; o >>= 1) {
        if (t < o) sh[t] += sh[t + o];
        __syncthreads();
    }
    if (t == 0) out[0] = (float)(-sh[0] / ((double)B * (double)B));
}

extern "C" void kernel_launch(void* const* d_in, const int* in_sizes, int n_in,
                              void* d_out, int out_size, void* d_ws, size_t ws_size,
                              hipStream_t stream) {
    const float* A = (const float*)d_in[0];
    const int* labels = (const int*)d_in[1];
    const float* Cov = (const float*)d_in[2];
    float* out = (float*)d_out;

    int B = in_sizes[0] / DIM;            // 4096
    int Jsplit = 16;
    int JSWEEP = B / (Jsplit * 64);       // 4
    int nP = Jsplit * 2;                  // 32 partials per row

    char* ws = (char*)d_ws;
    unsigned short* Wbf = (unsigned short*)ws;                       // B*128 bf16
    unsigned short* Abf = Wbf + (size_t)B * DIM;                     // B*128 bf16
    float* mP = (float*)(Abf + (size_t)B * DIM);                     // B*nP f32
    float* zP = mP + (size_t)B * nP;
    float* sP = zP + (size_t)B * nP;
    double* Sk = (double*)(sP + (size_t)B * nP);                     // B doubles

    prep_kernel<<<B / 2, 256, 0, stream>>>(A, labels, Cov, Wbf, Abf);
    main_kernel<<<(B / 128) * Jsplit, 256, 0, stream>>>(Wbf, Abf, mP, zP, sP,
                                                        Jsplit, JSWEEP, nP);
    combine_kernel<<<B, 64, 0, stream>>>(mP, zP, sP, Sk, B, nP);
    final_kernel<<<1, 1024, 0, stream>>>(Sk, labels, out, B);
}